// Round 13
// baseline (190.097 us; speedup 1.0000x reference)
//
#include <hip/hip_runtime.h>

#define HID 64
#define IN_DIM 128
#define RANGE_BITS 14
#define RANGE (1 << RANGE_BITS)   // 16384 nodes per bucket (64 KB LDS)
#define NB 7                      // ceil(100000 / 16384)
#define MCH 36                    // edge chunks
#define SCAN_TPB 512

// ---------------- dense: 4 waves/node-group, 16 channels per wave ----------------
// Block = 64 nodes. Wave w computes channels [16w,16w+16) for all 64 nodes (lane=node).
// z[node] = relu(x@W_in + b_in) . w_eff,  w_eff = W_g @ W_out
__global__ __launch_bounds__(256) void k_dense(const float* __restrict__ x,
                                               const float* __restrict__ W_in,
                                               const float* __restrict__ b_in,
                                               const float* __restrict__ W_g,
                                               const float* __restrict__ W_out,
                                               float* __restrict__ z, int N) {
    __shared__ float weff_l[HID];
    __shared__ float part[4][64];
    if (threadIdx.x < HID) {
        float s = 0.0f;
#pragma unroll
        for (int jp = 0; jp < HID; ++jp)
            s = fmaf(W_g[threadIdx.x * HID + jp], W_out[jp], s);
        weff_l[threadIdx.x] = s;
    }
    __syncthreads();

    const int wid  = threadIdx.x >> 6;    // channel group 0..3
    const int lane = threadIdx.x & 63;    // node within block
    int node = blockIdx.x * 64 + lane;
    if (node >= N) node = N - 1;          // clamped lanes duplicate-write identical values

    float acc[16];
#pragma unroll
    for (int jj = 0; jj < 16; ++jj)
        acc[jj] = b_in[wid * 16 + jj];    // wave-uniform -> s_load

    const float4* xrow = (const float4*)(x + (size_t)node * IN_DIM);
#pragma unroll 2
    for (int k4 = 0; k4 < IN_DIM / 4; ++k4) {
        float4 xv = xrow[k4];             // coalesced; 3/4 waves hit L1
        const float xk[4] = {xv.x, xv.y, xv.z, xv.w};
#pragma unroll
        for (int kk = 0; kk < 4; ++kk) {
            const float* wr = W_in + (k4 * 4 + kk) * HID + wid * 16;  // wave-uniform
#pragma unroll
            for (int jj = 0; jj < 16; ++jj)
                acc[jj] = fmaf(xk[kk], wr[jj], acc[jj]);
        }
    }

    float zv = 0.0f;
#pragma unroll
    for (int jj = 0; jj < 16; ++jj)
        zv = fmaf(fmaxf(acc[jj], 0.0f), weff_l[wid * 16 + jj], zv);
    part[wid][lane] = zv;
    __syncthreads();

    if (threadIdx.x < 64)
        z[node] = part[0][lane] + part[1][lane] + part[2][lane] + part[3][lane];
}

// ---------------- pass A: binned degree count (LDS atomics only) ----------------
__global__ __launch_bounds__(SCAN_TPB) void k_binA(const int* __restrict__ dst,
                                                   int* __restrict__ part,
                                                   int E, int chunk) {
    __shared__ int cnt[RANGE];
    for (int i = threadIdx.x; i < RANGE; i += SCAN_TPB) cnt[i] = 0;
    __syncthreads();

    const int r = blockIdx.x % NB;
    const int lo = r << RANGE_BITS;
    const int e0 = (blockIdx.x / NB) * chunk;
    const int e1 = min(E, e0 + chunk);
    for (int e = e0 + (int)threadIdx.x * 4; e + 3 < e1; e += SCAN_TPB * 4) {
        int4 d4 = *(const int4*)(dst + e);
        unsigned v;
        v = (unsigned)(d4.x - lo); if (v < RANGE) atomicAdd(&cnt[v], 1);
        v = (unsigned)(d4.y - lo); if (v < RANGE) atomicAdd(&cnt[v], 1);
        v = (unsigned)(d4.z - lo); if (v < RANGE) atomicAdd(&cnt[v], 1);
        v = (unsigned)(d4.w - lo); if (v < RANGE) atomicAdd(&cnt[v], 1);
    }
    __syncthreads();

    int* outp = part + (size_t)blockIdx.x * RANGE;
    for (int i = threadIdx.x; i < RANGE; i += SCAN_TPB) outp[i] = cnt[i];
}

// ---------------- reduce deg -> dinv, zs = z * dinv ----------------
__global__ __launch_bounds__(256) void k_redDeg(const int* __restrict__ part,
                                                const float* __restrict__ z,
                                                float* __restrict__ dinv,
                                                float* __restrict__ zs, int N) {
    int i = blockIdx.x * blockDim.x + threadIdx.x;
    if (i >= N) return;
    const int r = i >> RANGE_BITS, idx = i & (RANGE - 1);
    int d = 0;
#pragma unroll 4
    for (int m = 0; m < MCH; ++m)
        d += part[((size_t)m * NB + r) * RANGE + idx];
    float di = rsqrtf((float)d + 1.0f);
    dinv[i] = di;
    zs[i]   = z[i] * di;
}

// ---------------- pass C: binned value scatter (LDS float atomics only) ----------------
__global__ __launch_bounds__(SCAN_TPB) void k_binC(const int* __restrict__ eidx,
                                                   const float* __restrict__ zs,
                                                   float* __restrict__ partf,
                                                   int E, int chunk) {
    __shared__ float acc[RANGE];
    for (int i = threadIdx.x; i < RANGE; i += SCAN_TPB) acc[i] = 0.0f;
    __syncthreads();

    const int r = blockIdx.x % NB;
    const int lo = r << RANGE_BITS;
    const int e0 = (blockIdx.x / NB) * chunk;
    const int e1 = min(E, e0 + chunk);
    for (int e = e0 + (int)threadIdx.x * 4; e + 3 < e1; e += SCAN_TPB * 4) {
        int4 s4 = *(const int4*)(eidx + e);        // src
        int4 d4 = *(const int4*)(eidx + E + e);    // dst
        unsigned v;
        v = (unsigned)(d4.x - lo); if (v < RANGE) atomicAdd(&acc[v], zs[s4.x]);
        v = (unsigned)(d4.y - lo); if (v < RANGE) atomicAdd(&acc[v], zs[s4.y]);
        v = (unsigned)(d4.z - lo); if (v < RANGE) atomicAdd(&acc[v], zs[s4.z]);
        v = (unsigned)(d4.w - lo); if (v < RANGE) atomicAdd(&acc[v], zs[s4.w]);
    }
    __syncthreads();

    float* outp = partf + (size_t)blockIdx.x * RANGE;
    for (int i = threadIdx.x; i < RANGE; i += SCAN_TPB) outp[i] = acc[i];
}

// ------- final: out = dinv * (sum partials + zs[self]) + (b_g.W_out + b_out) -------
__global__ __launch_bounds__(256) void k_redFinal(const float* __restrict__ partf,
                                                  const float* __restrict__ dinv,
                                                  const float* __restrict__ zs,
                                                  const float* __restrict__ b_g,
                                                  const float* __restrict__ W_out,
                                                  const float* __restrict__ b_out,
                                                  float* __restrict__ out, int N) {
    const int lane = threadIdx.x & 63;
    float c = b_g[lane] * W_out[lane];
#pragma unroll
    for (int off = 32; off > 0; off >>= 1)
        c += __shfl_xor(c, off, 64);
    c += b_out[0];

    int i = blockIdx.x * blockDim.x + threadIdx.x;
    if (i >= N) return;
    const int r = i >> RANGE_BITS, idx = i & (RANGE - 1);
    float a = zs[i];   // self-loop
#pragma unroll 4
    for (int m = 0; m < MCH; ++m)
        a += partf[((size_t)m * NB + r) * RANGE + idx];
    out[i] = fmaf(dinv[i], a, c);
}

// ---------------- launch ----------------

extern "C" void kernel_launch(void* const* d_in, const int* in_sizes, int n_in,
                              void* d_out, int out_size, void* d_ws, size_t ws_size,
                              hipStream_t stream) {
    const float* x     = (const float*)d_in[0];
    const int*   eidx  = (const int*)d_in[1];
    const float* W_in  = (const float*)d_in[2];
    const float* b_in  = (const float*)d_in[3];
    const float* W_g   = (const float*)d_in[4];
    const float* b_g   = (const float*)d_in[5];
    const float* W_out = (const float*)d_in[6];
    const float* b_out = (const float*)d_in[7];
    float* out = (float*)d_out;

    const int N = in_sizes[0] / IN_DIM;   // 100000
    const int E = in_sizes[1] / 2;        // 1600000

    // chunk: multiple of 4 covering E with MCH chunks
    const int chunk = (((E + MCH - 1) / MCH) + 3) & ~3;

    // ws layout: part[NB*MCH*RANGE] (int/float, reused) | z[N] | dinv[N] | zs[N]
    const size_t partElems = (size_t)NB * MCH * RANGE;
    int*   part  = (int*)d_ws;
    float* partf = (float*)d_ws;          // reused after k_redDeg consumed counts
    float* z     = (float*)d_ws + partElems;
    float* dinv  = z + N;
    float* zs    = dinv + N;

    k_binA<<<NB * MCH, SCAN_TPB, 0, stream>>>(eidx + E, part, E, chunk);
    k_dense<<<(N + 63) / 64, 256, 0, stream>>>(x, W_in, b_in, W_g, W_out, z, N);
    k_redDeg<<<(N + 255) / 256, 256, 0, stream>>>(part, z, dinv, zs, N);
    k_binC<<<NB * MCH, SCAN_TPB, 0, stream>>>(eidx, zs, partf, E, chunk);
    k_redFinal<<<(N + 255) / 256, 256, 0, stream>>>(partf, dinv, zs, b_g, W_out, b_out, out, N);
}